// Round 1
// baseline (1785.927 us; speedup 1.0000x reference)
//
#include <hip/hip_runtime.h>

// VALSTM: B=256, T=512, IN=64, HS=128, gates=512.
// 16 blocks x 512 threads (8 waves). Each block owns 16 batch rows for all T.
// Weights preloaded once into registers as bf16 MFMA B-fragments.
// Per step: [attn: x@Wa + hc@Ua -> tanh -> @Va -> softmax -> xg] and
// [gates: xg@W + h@U + bias -> LSTM update], all via mfma_f32_16x16x32_bf16.
// 4 barriers/step. LDS tiles XOR-swizzled (byte ^= (row&7)<<4) to kill the
// 16-way bank conflict of row-strided fragment reads.

#define TSEQ 512
#define NB   256
#define DIN  64
#define DHS  128

typedef short bf16x8 __attribute__((ext_vector_type(8)));
typedef float f32x4  __attribute__((ext_vector_type(4)));

#define SWZ(off, row) ((off) ^ (((row) & 7) << 4))

__device__ __forceinline__ unsigned short f2bf(float f) {
  unsigned int x = __float_as_uint(f);
  x += 0x7fffu + ((x >> 16) & 1u);   // RNE
  return (unsigned short)(x >> 16);
}
__device__ __forceinline__ float bf2f(unsigned short u) {
  return __uint_as_float(((unsigned int)u) << 16);
}
__device__ __forceinline__ float sigm(float x)   { return 1.0f / (1.0f + __expf(-x)); }
__device__ __forceinline__ float tanh_f(float x) { return 1.0f - 2.0f / (1.0f + __expf(2.0f * x)); }

__global__ __launch_bounds__(512) void valstm_kernel(
    const float* __restrict__ X,  const float* __restrict__ W,  const float* __restrict__ U,
    const float* __restrict__ bias, const float* __restrict__ Wa, const float* __restrict__ Ua,
    const float* __restrict__ ba, const float* __restrict__ Va,
    const float* __restrict__ fcw, const float* __restrict__ fcb,
    float* __restrict__ out)
{
  const int tid = threadIdx.x;
  const int w   = tid >> 6;     // wave 0..7
  const int l   = tid & 63;
  const int lo  = l & 15;       // M/N index within tile
  const int hi  = l >> 4;       // K sub-block
  const int b0  = blockIdx.x * 16;

  // ---- LDS tiles (all bf16 except scores / final h) ----
  __shared__ __align__(16) unsigned short hc[16 * 256];     // h(0..127)|c(128..255), stride 512B
  __shared__ __align__(16) unsigned short xbuf2[2][16 * 64];// x bf16 double buffer, stride 128B
  __shared__ __align__(16) unsigned short ta[16 * 64];      // tanh(attn pre), stride 128B
  __shared__ __align__(16) unsigned short xg[16 * 64];      // alpha*x bf16, stride 128B
  __shared__ __align__(16) float a_s[16 * 64];              // attn scores f32, stride 256B
  __shared__ __align__(16) float hf[16 * 128];              // final-step h f32 (for y_pred)

  // ---- preload gate weights as B-fragments (bf16) ----
  // wave w owns hidden cols [16w, 16w+16); lane lo -> hid col, hi*8+e -> k
  bf16x8 Uf[4][4];   // [gate][ktile], K=128
  bf16x8 Wf[4][2];   // [gate][ktile], K=64
  float  biasr[4];
  const int hid = 16 * w + lo;
  #pragma unroll
  for (int g = 0; g < 4; ++g) {
    const int j = g * 128 + hid;
    biasr[g] = bias[j];
    #pragma unroll
    for (int kt = 0; kt < 4; ++kt) {
      bf16x8 v;
      #pragma unroll
      for (int e = 0; e < 8; ++e) {
        const int k = kt * 32 + hi * 8 + e;
        v[e] = (short)f2bf(U[k * 512 + j]);
      }
      Uf[g][kt] = v;
    }
    #pragma unroll
    for (int kt = 0; kt < 2; ++kt) {
      bf16x8 v;
      #pragma unroll
      for (int e = 0; e < 8; ++e) {
        const int k = kt * 32 + hi * 8 + e;
        v[e] = (short)f2bf(W[k * 512 + j]);
      }
      Wf[g][kt] = v;
    }
  }

  // ---- attention weights (waves 0..3 only): cols [16w,16w+16) of the 64 ----
  bf16x8 Uaf[8], Waf[2], Vaf[2];
  float  bar = 0.0f;
  if (w < 4) {
    const int ja = 16 * w + lo;
    bar = ba[ja];
    #pragma unroll
    for (int kt = 0; kt < 8; ++kt) {
      bf16x8 v;
      #pragma unroll
      for (int e = 0; e < 8; ++e) { const int k = kt * 32 + hi * 8 + e; v[e] = (short)f2bf(Ua[k * 64 + ja]); }
      Uaf[kt] = v;
    }
    #pragma unroll
    for (int kt = 0; kt < 2; ++kt) {
      bf16x8 v;
      #pragma unroll
      for (int e = 0; e < 8; ++e) { const int k = kt * 32 + hi * 8 + e; v[e] = (short)f2bf(Wa[k * 64 + ja]); }
      Waf[kt] = v;
    }
    #pragma unroll
    for (int kt = 0; kt < 2; ++kt) {
      bf16x8 v;
      #pragma unroll
      for (int e = 0; e < 8; ++e) { const int k = kt * 32 + hi * 8 + e; v[e] = (short)f2bf(Va[k * 64 + ja]); }
      Vaf[kt] = v;
    }
  }

  // ---- zero h,c in LDS (512 threads x 16B = 8KB) ----
  *(f32x4*)((char*)hc + tid * 16) = (f32x4){0.f, 0.f, 0.f, 0.f};

  // ---- x staging: thread -> (row xr, cols xc,xc+1); prefetch 1 step ahead ----
  const int xr = tid >> 5;            // 0..15
  const int xc = (tid & 31) * 2;      // 0..62
  const float* xptr = X + (size_t)(b0 + xr) * TSEQ * DIN + xc;
  {
    const float2 v0 = *(const float2*)(xptr + 0 * DIN);   // t=0
    const unsigned int p = (unsigned int)f2bf(v0.x) | ((unsigned int)f2bf(v0.y) << 16);
    *(unsigned int*)((char*)xbuf2[0] + SWZ(xr * 128 + xc * 2, xr)) = p;
  }
  float2 xf = *(const float2*)(xptr + 1 * DIN);           // prefetch t=1

  float cst[4] = {0.f, 0.f, 0.f, 0.f};                    // c state (row hi*4+ri, col hid)

  float* outY  = out;                                      // [256]
  float* outHS = out + 256;                                // [256,512,128]
  float* outHT = out + 256 + (size_t)NB * TSEQ * DHS;      // [256,128]
  float* outCT = outHT + NB * DHS;                         // [256,128]
  float* outAL = outCT + NB * DHS;                         // [256,64]

  __syncthreads();

  #pragma unroll 1
  for (int t = 0; t < TSEQ; ++t) {
    const int xb = t & 1;

    // A-fragments of h (shared by U-GEMM and Ua-GEMM)
    bf16x8 haf[4];
    #pragma unroll
    for (int kt = 0; kt < 4; ++kt)
      haf[kt] = *(const bf16x8*)((const char*)hc + SWZ(lo * 512 + (kt * 32 + hi * 8) * 2, lo));

    // ---- attention pre-activation (waves 0..3): x@Wa + [h,c]@Ua + ba ----
    f32x4 acc_a;
    if (w < 4) {
      acc_a = (f32x4){bar, bar, bar, bar};
      #pragma unroll
      for (int kt = 0; kt < 2; ++kt) {
        bf16x8 xa = *(const bf16x8*)((const char*)xbuf2[xb] + SWZ(lo * 128 + (kt * 32 + hi * 8) * 2, lo));
        acc_a = __builtin_amdgcn_mfma_f32_16x16x32_bf16(xa, Waf[kt], acc_a, 0, 0, 0);
      }
      #pragma unroll
      for (int kt = 0; kt < 4; ++kt)
        acc_a = __builtin_amdgcn_mfma_f32_16x16x32_bf16(haf[kt], Uaf[kt], acc_a, 0, 0, 0);
      #pragma unroll
      for (int kt = 4; kt < 8; ++kt) {
        bf16x8 ca = *(const bf16x8*)((const char*)hc + SWZ(lo * 512 + (kt * 32 + hi * 8) * 2, lo));
        acc_a = __builtin_amdgcn_mfma_f32_16x16x32_bf16(ca, Uaf[kt], acc_a, 0, 0, 0);
      }
    }

    // ---- U-GEMM (all waves), off the attention critical path ----
    f32x4 acc[4];
    #pragma unroll
    for (int g = 0; g < 4; ++g) {
      acc[g] = (f32x4){biasr[g], biasr[g], biasr[g], biasr[g]};
      #pragma unroll
      for (int kt = 0; kt < 4; ++kt)
        acc[g] = __builtin_amdgcn_mfma_f32_16x16x32_bf16(haf[kt], Uf[g][kt], acc[g], 0, 0, 0);
    }

    // tanh -> ta (bf16)
    if (w < 4) {
      #pragma unroll
      for (int ri = 0; ri < 4; ++ri) {
        const int rr = hi * 4 + ri;                        // C-layout row
        const float tv = tanh_f(acc_a[ri]);
        *(unsigned short*)((char*)ta + SWZ(rr * 128 + (16 * w + lo) * 2, rr)) = f2bf(tv);
      }
    }
    __syncthreads();  // (2) ta ready

    // ---- Va-GEMM, scores -> a_s f32 ----
    if (w < 4) {
      f32x4 av = (f32x4){0.f, 0.f, 0.f, 0.f};
      #pragma unroll
      for (int kt = 0; kt < 2; ++kt) {
        bf16x8 tf = *(const bf16x8*)((const char*)ta + SWZ(lo * 128 + (kt * 32 + hi * 8) * 2, lo));
        av = __builtin_amdgcn_mfma_f32_16x16x32_bf16(tf, Vaf[kt], av, 0, 0, 0);
      }
      #pragma unroll
      for (int ri = 0; ri < 4; ++ri) {
        const int rr = hi * 4 + ri;
        *(float*)((char*)a_s + SWZ(rr * 256 + (16 * w + lo) * 4, rr)) = av[ri];
      }
    }
    __syncthreads();  // (3) scores ready

    // ---- softmax + xg (threads 0..255: row r, 4 cols each) ----
    if (tid < 256) {
      const int r = tid >> 4, sg = tid & 15;
      f32x4 v = *(const f32x4*)((const char*)a_s + SWZ(r * 256 + sg * 16, r));
      float m = fmaxf(fmaxf(v[0], v[1]), fmaxf(v[2], v[3]));
      #pragma unroll
      for (int s = 1; s < 16; s <<= 1) m = fmaxf(m, __shfl_xor(m, s));
      float e0 = __expf(v[0] - m), e1 = __expf(v[1] - m), e2 = __expf(v[2] - m), e3 = __expf(v[3] - m);
      float s4 = e0 + e1 + e2 + e3;
      #pragma unroll
      for (int s = 1; s < 16; s <<= 1) s4 += __shfl_xor(s4, s);
      const float rinv = 1.0f / s4;
      const float al0 = e0 * rinv, al1 = e1 * rinv, al2 = e2 * rinv, al3 = e3 * rinv;
      const unsigned long long xp =
          *(const unsigned long long*)((const char*)xbuf2[xb] + SWZ(r * 128 + sg * 8, r));
      const float x0 = bf2f((unsigned short)xp),         x1 = bf2f((unsigned short)(xp >> 16));
      const float x2 = bf2f((unsigned short)(xp >> 32)), x3 = bf2f((unsigned short)(xp >> 48));
      const unsigned int p0 = (unsigned int)f2bf(al0 * x0) | ((unsigned int)f2bf(al1 * x1) << 16);
      const unsigned int p1 = (unsigned int)f2bf(al2 * x2) | ((unsigned int)f2bf(al3 * x3) << 16);
      *(unsigned long long*)((char*)xg + SWZ(r * 128 + sg * 8, r)) =
          (unsigned long long)p0 | ((unsigned long long)p1 << 32);
      if (t == TSEQ - 1) {
        *(f32x4*)(outAL + (b0 + r) * 64 + sg * 4) = (f32x4){al0, al1, al2, al3};
      }
    }
    __syncthreads();  // (4) xg ready

    // ---- W-GEMM: gates += xg @ W ----
    #pragma unroll
    for (int kt = 0; kt < 2; ++kt) {
      bf16x8 xgf = *(const bf16x8*)((const char*)xg + SWZ(lo * 128 + (kt * 32 + hi * 8) * 2, lo));
      #pragma unroll
      for (int g = 0; g < 4; ++g)
        acc[g] = __builtin_amdgcn_mfma_f32_16x16x32_bf16(xgf, Wf[g][kt], acc[g], 0, 0, 0);
    }

    // ---- LSTM update + state/output writes ----
    #pragma unroll
    for (int ri = 0; ri < 4; ++ri) {
      const int rr = hi * 4 + ri;
      const float iv = sigm(acc[0][ri]);
      const float fv = sigm(acc[1][ri]);
      const float gv = tanh_f(acc[2][ri]);
      const float ov = sigm(acc[3][ri]);
      const float cn = fv * cst[ri] + iv * gv;
      const float hv = ov * tanh_f(cn);
      cst[ri] = cn;
      *(unsigned short*)((char*)hc + SWZ(rr * 512 + hid * 2, rr))         = f2bf(hv);
      *(unsigned short*)((char*)hc + SWZ(rr * 512 + (128 + hid) * 2, rr)) = f2bf(cn);
      outHS[((size_t)(b0 + rr) * TSEQ + t) * DHS + hid] = hv;
      if (t == TSEQ - 1) {
        outHT[(b0 + rr) * DHS + hid] = hv;
        outCT[(b0 + rr) * DHS + hid] = cn;
        hf[rr * 128 + hid] = hv;
      }
    }

    // ---- stage x for t+1, prefetch t+2 ----
    {
      const unsigned int p = (unsigned int)f2bf(xf.x) | ((unsigned int)f2bf(xf.y) << 16);
      *(unsigned int*)((char*)xbuf2[(t + 1) & 1] + SWZ(xr * 128 + xc * 2, xr)) = p;
      const int tn = t + 2;
      if (tn < TSEQ) xf = *(const float2*)(xptr + tn * DIN);
    }
    __syncthreads();  // (1) end of step: hc, x(t+1) visible
  }

  // ---- y_pred = h_T @ fc_w + fc_b (wave 0, f32 h from LDS) ----
  if (w == 0) {
    const float fw0 = fcw[l], fw1 = fcw[64 + l];
    const float fb = fcb[0];
    #pragma unroll 1
    for (int r = 0; r < 16; ++r) {
      float s = hf[r * 128 + l] * fw0 + hf[r * 128 + 64 + l] * fw1;
      #pragma unroll
      for (int msk = 1; msk < 64; msk <<= 1) s += __shfl_xor(s, msk);
      if (l == 0) outY[b0 + r] = s + fb;
    }
  }
}

extern "C" void kernel_launch(void* const* d_in, const int* in_sizes, int n_in,
                              void* d_out, int out_size, void* d_ws, size_t ws_size,
                              hipStream_t stream) {
  const float* X    = (const float*)d_in[0];
  const float* W    = (const float*)d_in[1];
  const float* U    = (const float*)d_in[2];
  const float* bias = (const float*)d_in[3];
  const float* Wa   = (const float*)d_in[4];
  const float* Ua   = (const float*)d_in[5];
  const float* ba   = (const float*)d_in[6];
  const float* Va   = (const float*)d_in[7];
  const float* fcw  = (const float*)d_in[8];
  const float* fcb  = (const float*)d_in[9];
  valstm_kernel<<<16, 512, 0, stream>>>(X, W, U, bias, Wa, Ua, ba, Va, fcw, fcb, (float*)d_out);
}

// Round 2
// 1729.721 us; speedup vs baseline: 1.0325x; 1.0325x over previous
//
#include <hip/hip_runtime.h>

// VALSTM: B=256, T=512, IN=64, HS=128, gates=512.
// 16 blocks x 512 threads (8 waves). Each block owns 16 batch rows for all T.
// Weights preloaded once into registers as bf16 MFMA B-fragments.
// Per step (3 raw barriers, LDS-only waits):
//   [attn pre: x@Wa + hc@Ua (split chains) -> tanh -> ta]  bar(2)
//   [Va-GEMM TRANSPOSED (S^T = Va^T @ ta^T) -> exp -> in-wave row sums] bar(3)
//   [consumers rebuild xg = softmax*x inline -> W-GEMM -> LSTM update -> hc] bar(1)
// Raw barriers wait lgkmcnt only: outHS stores + x prefetch float across steps.
// LDS tiles XOR-swizzled (byte ^= (row&7)<<4) against row-strided 16-way conflicts.

#define TSEQ 512
#define NB   256
#define DIN  64
#define DHS  128

typedef short bf16x8 __attribute__((ext_vector_type(8)));
typedef float f32x4  __attribute__((ext_vector_type(4)));

#define SWZ(off, row) ((off) ^ (((row) & 7) << 4))

__device__ __forceinline__ void bar_lds() {
  // LDS-producer/consumer barrier WITHOUT vmcnt drain (unlike __syncthreads).
  asm volatile("s_waitcnt lgkmcnt(0)\n\ts_barrier" ::: "memory");
}

__device__ __forceinline__ unsigned short f2bf(float f) {
  unsigned int x = __float_as_uint(f);
  x += 0x7fffu + ((x >> 16) & 1u);   // RNE
  return (unsigned short)(x >> 16);
}
__device__ __forceinline__ float bf2f(unsigned short u) {
  return __uint_as_float(((unsigned int)u) << 16);
}
__device__ __forceinline__ float sigm(float x)   { return 1.0f / (1.0f + __expf(-x)); }
__device__ __forceinline__ float tanh_f(float x) { return 1.0f - 2.0f / (1.0f + __expf(2.0f * x)); }

__global__ __launch_bounds__(512) void valstm_kernel(
    const float* __restrict__ X,  const float* __restrict__ W,  const float* __restrict__ U,
    const float* __restrict__ bias, const float* __restrict__ Wa, const float* __restrict__ Ua,
    const float* __restrict__ ba, const float* __restrict__ Va,
    const float* __restrict__ fcw, const float* __restrict__ fcb,
    float* __restrict__ out)
{
  const int tid = threadIdx.x;
  const int w   = tid >> 6;     // wave 0..7
  const int l   = tid & 63;
  const int lo  = l & 15;       // M/N index within tile
  const int hi  = l >> 4;       // K sub-block
  const int b0  = blockIdx.x * 16;

  // ---- LDS ----
  __shared__ __align__(16) unsigned short hc[16 * 256];      // h|c bf16, stride 512B
  __shared__ __align__(16) unsigned short xbuf2[2][16 * 64]; // x bf16 dbuf, stride 128B
  __shared__ __align__(16) unsigned short ta[16 * 64];       // tanh(attn pre), stride 128B
  __shared__ __align__(16) float a_s[16 * 64];               // exp(scores) f32, stride 256B
  __shared__ __align__(16) float S4[64];                     // per-(row,wave) partial sums
  __shared__ __align__(16) float hf[16 * 128];               // final-step h f32

  // ---- gate weights as B-fragments ----
  bf16x8 Uf[4][4];   // [gate][ktile], K=128
  bf16x8 Wf[4][2];   // [gate][ktile], K=64
  float  biasr[4];
  const int hid = 16 * w + lo;
  #pragma unroll
  for (int g = 0; g < 4; ++g) {
    const int j = g * 128 + hid;
    biasr[g] = bias[j];
    #pragma unroll
    for (int kt = 0; kt < 4; ++kt) {
      bf16x8 v;
      #pragma unroll
      for (int e = 0; e < 8; ++e) { const int k = kt * 32 + hi * 8 + e; v[e] = (short)f2bf(U[k * 512 + j]); }
      Uf[g][kt] = v;
    }
    #pragma unroll
    for (int kt = 0; kt < 2; ++kt) {
      bf16x8 v;
      #pragma unroll
      for (int e = 0; e < 8; ++e) { const int k = kt * 32 + hi * 8 + e; v[e] = (short)f2bf(W[k * 512 + j]); }
      Wf[g][kt] = v;
    }
  }

  // ---- attention weights (waves 0..3): cols [16w,16w+16) ----
  bf16x8 Uaf[8], Waf[2], Vaf[2];
  float  bar = 0.0f;
  if (w < 4) {
    const int ja = 16 * w + lo;
    bar = ba[ja];
    #pragma unroll
    for (int kt = 0; kt < 8; ++kt) {
      bf16x8 v;
      #pragma unroll
      for (int e = 0; e < 8; ++e) { const int k = kt * 32 + hi * 8 + e; v[e] = (short)f2bf(Ua[k * 64 + ja]); }
      Uaf[kt] = v;
    }
    #pragma unroll
    for (int kt = 0; kt < 2; ++kt) {
      bf16x8 v;
      #pragma unroll
      for (int e = 0; e < 8; ++e) { const int k = kt * 32 + hi * 8 + e; v[e] = (short)f2bf(Wa[k * 64 + ja]); }
      Waf[kt] = v;
    }
    #pragma unroll
    for (int kt = 0; kt < 2; ++kt) {
      // Va[k][ja] serves BOTH as B-frag (old) and as A-frag of Va^T (new) — same regs.
      bf16x8 v;
      #pragma unroll
      for (int e = 0; e < 8; ++e) { const int k = kt * 32 + hi * 8 + e; v[e] = (short)f2bf(Va[k * 64 + ja]); }
      Vaf[kt] = v;
    }
  }

  // ---- zero h,c ----
  *(f32x4*)((char*)hc + tid * 16) = (f32x4){0.f, 0.f, 0.f, 0.f};

  // ---- x staging ----
  const int xr = tid >> 5;            // 0..15
  const int xc = (tid & 31) * 2;      // 0..62
  const float* xptr = X + (size_t)(b0 + xr) * TSEQ * DIN + xc;
  {
    const float2 v0 = *(const float2*)(xptr + 0 * DIN);   // t=0
    const unsigned int p = (unsigned int)f2bf(v0.x) | ((unsigned int)f2bf(v0.y) << 16);
    *(unsigned int*)((char*)xbuf2[0] + SWZ(xr * 128 + xc * 2, xr)) = p;
  }
  float2 xf = *(const float2*)(xptr + 1 * DIN);           // prefetch t=1

  float cst[4] = {0.f, 0.f, 0.f, 0.f};

  float* outY  = out;
  float* outHS = out + 256;
  float* outHT = out + 256 + (size_t)NB * TSEQ * DHS;
  float* outCT = outHT + NB * DHS;
  float* outAL = outCT + NB * DHS;

  bar_lds();

  #pragma unroll 1
  for (int t = 0; t < TSEQ; ++t) {
    const int xb = t & 1;

    // A-fragments of h (shared by U-GEMM and Ua-GEMM)
    bf16x8 haf[4];
    #pragma unroll
    for (int kt = 0; kt < 4; ++kt)
      haf[kt] = *(const bf16x8*)((const char*)hc + SWZ(lo * 512 + (kt * 32 + hi * 8) * 2, lo));

    // ---- attention pre-activation (waves 0..3), 3 parallel chains ----
    f32x4 pre;
    if (w < 4) {
      f32x4 aa = (f32x4){bar, bar, bar, bar};
      f32x4 ah = (f32x4){0.f, 0.f, 0.f, 0.f};
      f32x4 ac = (f32x4){0.f, 0.f, 0.f, 0.f};
      #pragma unroll
      for (int kt = 0; kt < 2; ++kt) {
        bf16x8 xa = *(const bf16x8*)((const char*)xbuf2[xb] + SWZ(lo * 128 + (kt * 32 + hi * 8) * 2, lo));
        aa = __builtin_amdgcn_mfma_f32_16x16x32_bf16(xa, Waf[kt], aa, 0, 0, 0);
      }
      #pragma unroll
      for (int kt = 0; kt < 4; ++kt)
        ah = __builtin_amdgcn_mfma_f32_16x16x32_bf16(haf[kt], Uaf[kt], ah, 0, 0, 0);
      #pragma unroll
      for (int kt = 4; kt < 8; ++kt) {
        bf16x8 ca = *(const bf16x8*)((const char*)hc + SWZ(lo * 512 + (kt * 32 + hi * 8) * 2, lo));
        ac = __builtin_amdgcn_mfma_f32_16x16x32_bf16(ca, Uaf[kt], ac, 0, 0, 0);
      }
      pre = aa + ah + ac;
    }

    // ---- U-GEMM (all waves) ----
    f32x4 acc[4];
    #pragma unroll
    for (int g = 0; g < 4; ++g) {
      acc[g] = (f32x4){biasr[g], biasr[g], biasr[g], biasr[g]};
      #pragma unroll
      for (int kt = 0; kt < 4; ++kt)
        acc[g] = __builtin_amdgcn_mfma_f32_16x16x32_bf16(haf[kt], Uf[g][kt], acc[g], 0, 0, 0);
    }

    if (w < 4) {
      #pragma unroll
      for (int ri = 0; ri < 4; ++ri) {
        const int rr = hi * 4 + ri;
        *(unsigned short*)((char*)ta + SWZ(rr * 128 + (16 * w + lo) * 2, rr)) = f2bf(tanh_f(pre[ri]));
      }
    }
    bar_lds();  // (2) ta ready

    // ---- Va-GEMM transposed: S^T = Va^T @ ta^T; lane holds 4 scores of batch row lo ----
    if (w < 4) {
      f32x4 av = (f32x4){0.f, 0.f, 0.f, 0.f};
      #pragma unroll
      for (int kt = 0; kt < 2; ++kt) {
        bf16x8 tf = *(const bf16x8*)((const char*)ta + SWZ(lo * 128 + (kt * 32 + hi * 8) * 2, lo));
        av = __builtin_amdgcn_mfma_f32_16x16x32_bf16(Vaf[kt], tf, av, 0, 0, 0);  // swapped operands
      }
      // scores bounded (|s| <= 64*0.089): exp without max-subtraction
      f32x4 ev;
      #pragma unroll
      for (int ri = 0; ri < 4; ++ri) ev[ri] = __expf(av[ri]);
      float ps = ev[0] + ev[1] + ev[2] + ev[3];
      ps += __shfl_xor(ps, 16);
      ps += __shfl_xor(ps, 32);
      *(f32x4*)((char*)a_s + SWZ(lo * 256 + (16 * w + hi * 4) * 4, lo)) = ev;  // e[row lo][j=16w+hi*4+ri]
      if (hi == 0) S4[lo * 4 + w] = ps;
    }
    bar_lds();  // (3) e + partial sums ready

    if (t == TSEQ - 1 && tid < 256) {   // alpha output (last step only)
      const int r = tid >> 4, sg = tid & 15;
      f32x4 e4 = *(const f32x4*)((const char*)a_s + SWZ(r * 256 + sg * 16, r));
      const f32x4 s4v = *(const f32x4*)(S4 + r * 4);
      const float rinv = 1.0f / (s4v[0] + s4v[1] + s4v[2] + s4v[3]);
      *(f32x4*)(outAL + (b0 + r) * 64 + sg * 4) =
          (f32x4){e4[0] * rinv, e4[1] * rinv, e4[2] * rinv, e4[3] * rinv};
    }

    // ---- inline xg = (e*rinv)*x + W-GEMM (all 8 waves) ----
    {
      const f32x4 s4v = *(const f32x4*)(S4 + lo * 4);
      const float rinv = 1.0f / (s4v[0] + s4v[1] + s4v[2] + s4v[3]);
      #pragma unroll
      for (int kt = 0; kt < 2; ++kt) {
        const f32x4 elo = *(const f32x4*)((const char*)a_s + SWZ(lo * 256 + kt * 128 + hi * 32, lo));
        const f32x4 ehi = *(const f32x4*)((const char*)a_s + SWZ(lo * 256 + kt * 128 + hi * 32 + 16, lo));
        const bf16x8 xv = *(const bf16x8*)((const char*)xbuf2[xb] + SWZ(lo * 128 + (kt * 32 + hi * 8) * 2, lo));
        bf16x8 xgf;
        #pragma unroll
        for (int e = 0; e < 4; ++e) xgf[e] = (short)f2bf(elo[e] * rinv * bf2f((unsigned short)xv[e]));
        #pragma unroll
        for (int e = 4; e < 8; ++e) xgf[e] = (short)f2bf(ehi[e - 4] * rinv * bf2f((unsigned short)xv[e]));
        #pragma unroll
        for (int g = 0; g < 4; ++g)
          acc[g] = __builtin_amdgcn_mfma_f32_16x16x32_bf16(xgf, Wf[g][kt], acc[g], 0, 0, 0);
      }
    }

    // ---- LSTM update + state/output writes ----
    #pragma unroll
    for (int ri = 0; ri < 4; ++ri) {
      const int rr = hi * 4 + ri;
      const float iv = sigm(acc[0][ri]);
      const float fv = sigm(acc[1][ri]);
      const float gv = tanh_f(acc[2][ri]);
      const float ov = sigm(acc[3][ri]);
      const float cn = fv * cst[ri] + iv * gv;
      const float hv = ov * tanh_f(cn);
      cst[ri] = cn;
      *(unsigned short*)((char*)hc + SWZ(rr * 512 + hid * 2, rr))         = f2bf(hv);
      *(unsigned short*)((char*)hc + SWZ(rr * 512 + (128 + hid) * 2, rr)) = f2bf(cn);
      outHS[((size_t)(b0 + rr) * TSEQ + t) * DHS + hid] = hv;   // fire-and-forget
      if (t == TSEQ - 1) {
        outHT[(b0 + rr) * DHS + hid] = hv;
        outCT[(b0 + rr) * DHS + hid] = cn;
        hf[rr * 128 + hid] = hv;
      }
    }

    // ---- stage x(t+1), prefetch t+2 (never drained at barriers) ----
    {
      const unsigned int p = (unsigned int)f2bf(xf.x) | ((unsigned int)f2bf(xf.y) << 16);
      *(unsigned int*)((char*)xbuf2[(t + 1) & 1] + SWZ(xr * 128 + xc * 2, xr)) = p;
      const int tn = t + 2;
      if (tn < TSEQ) xf = *(const float2*)(xptr + tn * DIN);
    }
    bar_lds();  // (1) end of step: hc, x(t+1) visible
  }

  // ---- y_pred = h_T @ fc_w + fc_b (waves 0..3, 4 rows each) ----
  if (w < 4) {
    const float fw0 = fcw[l], fw1 = fcw[64 + l];
    const float fb = fcb[0];
    #pragma unroll
    for (int rr = 0; rr < 4; ++rr) {
      const int r = w * 4 + rr;
      float s = hf[r * 128 + l] * fw0 + hf[r * 128 + 64 + l] * fw1;
      #pragma unroll
      for (int msk = 1; msk < 64; msk <<= 1) s += __shfl_xor(s, msk);
      if (l == 0) outY[b0 + r] = s + fb;
    }
  }
}

extern "C" void kernel_launch(void* const* d_in, const int* in_sizes, int n_in,
                              void* d_out, int out_size, void* d_ws, size_t ws_size,
                              hipStream_t stream) {
  const float* X    = (const float*)d_in[0];
  const float* W    = (const float*)d_in[1];
  const float* U    = (const float*)d_in[2];
  const float* bias = (const float*)d_in[3];
  const float* Wa   = (const float*)d_in[4];
  const float* Ua   = (const float*)d_in[5];
  const float* ba   = (const float*)d_in[6];
  const float* Va   = (const float*)d_in[7];
  const float* fcw  = (const float*)d_in[8];
  const float* fcb  = (const float*)d_in[9];
  valstm_kernel<<<16, 512, 0, stream>>>(X, W, U, bias, Wa, Ua, ba, Va, fcw, fcb, (float*)d_out);
}

// Round 3
// 1357.099 us; speedup vs baseline: 1.3160x; 1.2746x over previous
//
#include <hip/hip_runtime.h>

// VALSTM: B=256, T=512, IN=64, HS=128, gates=512.
// 16 blocks x 512 threads (8 waves). Each block owns 16 batch rows for all T.
// Weights preloaded once into registers as bf16 MFMA B-fragments.
// Per step (3 raw lgkmcnt-only barriers):
//   [attn pre: x@Wa + hc@Ua (3 chains) -> tanh -> ta]  bar(2)
//   [Va-GEMM transposed -> exp -> in-wave row sums] bar(3)
//   [xg rebuilt inline -> W-GEMM -> LSTM update -> hc] bar(1)
// Round 2: VALU-issue diet — rcp/exp2 activations (no IEEE div), 2-op bf16
// rounding, hoisted swizzled LDS offsets, incremental outHS pointers.

#define TSEQ 512
#define NB   256
#define DIN  64
#define DHS  128
#define LOG2E 1.44269504f

typedef short bf16x8 __attribute__((ext_vector_type(8)));
typedef float f32x4  __attribute__((ext_vector_type(4)));
typedef unsigned int u32x4 __attribute__((ext_vector_type(4)));

#define SWZ(off, row) ((off) ^ (((row) & 7) << 4))

__device__ __forceinline__ void bar_lds() {
  asm volatile("s_waitcnt lgkmcnt(0)\n\ts_barrier" ::: "memory");
}

__device__ __forceinline__ float fexp2(float x) { return __builtin_amdgcn_exp2f(x); }
__device__ __forceinline__ float frcp(float x)  { return __builtin_amdgcn_rcpf(x); }
__device__ __forceinline__ float sigm(float x)   { return frcp(1.0f + fexp2(-LOG2E * x)); }
__device__ __forceinline__ float tanh_f(float x) { return 1.0f - 2.0f * frcp(1.0f + fexp2(2.0f * LOG2E * x)); }

// round-to-nearest (ties up): 2 VALU ops
__device__ __forceinline__ unsigned short f2bf(float f) {
  return (unsigned short)((__float_as_uint(f) + 0x8000u) >> 16);
}
// pack two floats -> bf16x2 in one u32: 5 VALU ops
__device__ __forceinline__ unsigned int pack2(float a, float b) {
  return ((__float_as_uint(a) + 0x8000u) >> 16) | ((__float_as_uint(b) + 0x8000u) & 0xffff0000u);
}
__device__ __forceinline__ float bf2f(unsigned short u) {
  return __uint_as_float(((unsigned int)u) << 16);
}

__global__ __launch_bounds__(512, 2) void valstm_kernel(
    const float* __restrict__ X,  const float* __restrict__ W,  const float* __restrict__ U,
    const float* __restrict__ bias, const float* __restrict__ Wa, const float* __restrict__ Ua,
    const float* __restrict__ ba, const float* __restrict__ Va,
    const float* __restrict__ fcw, const float* __restrict__ fcb,
    float* __restrict__ out)
{
  const int tid = threadIdx.x;
  const int w   = tid >> 6;     // wave 0..7
  const int l   = tid & 63;
  const int lo  = l & 15;       // M/N index within tile
  const int hi  = l >> 4;       // K sub-block
  const int b0  = blockIdx.x * 16;

  // ---- LDS ----
  __shared__ __align__(16) unsigned short hc[16 * 256];      // h|c bf16, stride 512B
  __shared__ __align__(16) unsigned short xbuf2[2][16 * 64]; // x bf16 dbuf, stride 128B
  __shared__ __align__(16) unsigned short ta[16 * 64];       // tanh(attn pre), stride 128B
  __shared__ __align__(16) float a_s[16 * 64];               // exp(scores) f32, stride 256B
  __shared__ __align__(16) float S4[64];                     // per-(row,wave) partial sums
  __shared__ __align__(16) float hf[16 * 128];               // final-step h f32

  // ---- gate weights as B-fragments ----
  bf16x8 Uf[4][4];   // [gate][ktile], K=128
  bf16x8 Wf[4][2];   // [gate][ktile], K=64
  float  biasr[4];
  const int hid = 16 * w + lo;
  #pragma unroll
  for (int g = 0; g < 4; ++g) {
    const int j = g * 128 + hid;
    biasr[g] = bias[j];
    #pragma unroll
    for (int kt = 0; kt < 4; ++kt) {
      bf16x8 v;
      #pragma unroll
      for (int e = 0; e < 8; ++e) { const int k = kt * 32 + hi * 8 + e; v[e] = (short)f2bf(U[k * 512 + j]); }
      Uf[g][kt] = v;
    }
    #pragma unroll
    for (int kt = 0; kt < 2; ++kt) {
      bf16x8 v;
      #pragma unroll
      for (int e = 0; e < 8; ++e) { const int k = kt * 32 + hi * 8 + e; v[e] = (short)f2bf(W[k * 512 + j]); }
      Wf[g][kt] = v;
    }
  }

  // ---- attention weights (waves 0..3): cols [16w,16w+16) ----
  bf16x8 Uaf[8], Waf[2], Vaf[2];
  float  bar = 0.0f;
  if (w < 4) {
    const int ja = 16 * w + lo;
    bar = ba[ja];
    #pragma unroll
    for (int kt = 0; kt < 8; ++kt) {
      bf16x8 v;
      #pragma unroll
      for (int e = 0; e < 8; ++e) { const int k = kt * 32 + hi * 8 + e; v[e] = (short)f2bf(Ua[k * 64 + ja]); }
      Uaf[kt] = v;
    }
    #pragma unroll
    for (int kt = 0; kt < 2; ++kt) {
      bf16x8 v;
      #pragma unroll
      for (int e = 0; e < 8; ++e) { const int k = kt * 32 + hi * 8 + e; v[e] = (short)f2bf(Wa[k * 64 + ja]); }
      Waf[kt] = v;
    }
    #pragma unroll
    for (int kt = 0; kt < 2; ++kt) {
      bf16x8 v;
      #pragma unroll
      for (int e = 0; e < 8; ++e) { const int k = kt * 32 + hi * 8 + e; v[e] = (short)f2bf(Va[k * 64 + ja]); }
      Vaf[kt] = v;
    }
  }

  // ---- hoisted swizzled LDS byte-offsets (loop-invariant) ----
  int haf_off[4], caf_off[4], xa_off[2], as_rd[2][2];
  #pragma unroll
  for (int kt = 0; kt < 4; ++kt) {
    haf_off[kt] = SWZ(lo * 512 + (kt * 32 + hi * 8) * 2, lo);
    caf_off[kt] = SWZ(lo * 512 + ((kt + 4) * 32 + hi * 8) * 2, lo);
  }
  #pragma unroll
  for (int kt = 0; kt < 2; ++kt) {
    xa_off[kt] = SWZ(lo * 128 + (kt * 32 + hi * 8) * 2, lo);   // also ta-read, xv-read
    as_rd[kt][0] = SWZ(lo * 256 + kt * 128 + hi * 32, lo);
    as_rd[kt][1] = SWZ(lo * 256 + kt * 128 + hi * 32 + 16, lo);
  }
  int ta_st[4], hc_h[4], hc_c[4];
  #pragma unroll
  for (int ri = 0; ri < 4; ++ri) {
    const int rr = hi * 4 + ri;
    ta_st[ri] = SWZ(rr * 128 + (16 * w + lo) * 2, rr);
    hc_h[ri]  = SWZ(rr * 512 + hid * 2, rr);
    hc_c[ri]  = SWZ(rr * 512 + (128 + hid) * 2, rr);
  }
  const int as_st = SWZ(lo * 256 + (16 * w + hi * 4) * 4, lo);

  // ---- zero h,c ----
  *(f32x4*)((char*)hc + tid * 16) = (f32x4){0.f, 0.f, 0.f, 0.f};

  // ---- x staging ----
  const int xr = tid >> 5;            // 0..15
  const int xc = (tid & 31) * 2;      // 0..62
  const int xst_off = SWZ(xr * 128 + xc * 2, xr);
  const float* xptr = X + (size_t)(b0 + xr) * TSEQ * DIN + xc;
  {
    const float2 v0 = *(const float2*)(xptr + 0 * DIN);   // t=0
    *(unsigned int*)((char*)xbuf2[0] + xst_off) = pack2(v0.x, v0.y);
  }
  float2 xf = *(const float2*)(xptr + 1 * DIN);           // prefetch t=1

  float cst[4] = {0.f, 0.f, 0.f, 0.f};

  float* outY  = out;
  float* outHS = out + 256;
  float* outHT = out + 256 + (size_t)NB * TSEQ * DHS;
  float* outCT = outHT + NB * DHS;
  float* outAL = outCT + NB * DHS;

  // incremental hidden-seq store pointers (row rr = hi*4+ri, col hid)
  float* hsP[4];
  #pragma unroll
  for (int ri = 0; ri < 4; ++ri)
    hsP[ri] = outHS + (size_t)(b0 + hi * 4 + ri) * TSEQ * DHS + hid;

  bar_lds();

  #pragma unroll 1
  for (int t = 0; t < TSEQ; ++t) {
    const int xoff = (t & 1) << 11;   // xbuf2 double-buffer byte offset (2048)

    // A-fragments of h (shared by U-GEMM and Ua-GEMM)
    bf16x8 haf[4];
    #pragma unroll
    for (int kt = 0; kt < 4; ++kt)
      haf[kt] = *(const bf16x8*)((const char*)hc + haf_off[kt]);

    // ---- attention pre-activation (waves 0..3), 3 parallel chains ----
    f32x4 pre;
    if (w < 4) {
      f32x4 aa = (f32x4){bar, bar, bar, bar};
      f32x4 ah = (f32x4){0.f, 0.f, 0.f, 0.f};
      f32x4 ac = (f32x4){0.f, 0.f, 0.f, 0.f};
      #pragma unroll
      for (int kt = 0; kt < 2; ++kt) {
        bf16x8 xa = *(const bf16x8*)((const char*)xbuf2[0] + xoff + xa_off[kt]);
        aa = __builtin_amdgcn_mfma_f32_16x16x32_bf16(xa, Waf[kt], aa, 0, 0, 0);
      }
      #pragma unroll
      for (int kt = 0; kt < 4; ++kt)
        ah = __builtin_amdgcn_mfma_f32_16x16x32_bf16(haf[kt], Uaf[kt], ah, 0, 0, 0);
      #pragma unroll
      for (int kt = 0; kt < 4; ++kt) {
        bf16x8 ca = *(const bf16x8*)((const char*)hc + caf_off[kt]);
        ac = __builtin_amdgcn_mfma_f32_16x16x32_bf16(ca, Uaf[kt + 4], ac, 0, 0, 0);
      }
      pre = aa + ah + ac;
    }

    // ---- U-GEMM (all waves) ----
    f32x4 acc[4];
    #pragma unroll
    for (int g = 0; g < 4; ++g) {
      acc[g] = (f32x4){biasr[g], biasr[g], biasr[g], biasr[g]};
      #pragma unroll
      for (int kt = 0; kt < 4; ++kt)
        acc[g] = __builtin_amdgcn_mfma_f32_16x16x32_bf16(haf[kt], Uf[g][kt], acc[g], 0, 0, 0);
    }

    if (w < 4) {
      #pragma unroll
      for (int ri = 0; ri < 4; ++ri)
        *(unsigned short*)((char*)ta + ta_st[ri]) = f2bf(tanh_f(pre[ri]));
    }
    bar_lds();  // (2) ta ready

    // ---- Va-GEMM transposed: lane holds 4 scores of batch row lo ----
    if (w < 4) {
      f32x4 av = (f32x4){0.f, 0.f, 0.f, 0.f};
      #pragma unroll
      for (int kt = 0; kt < 2; ++kt) {
        bf16x8 tf = *(const bf16x8*)((const char*)ta + xa_off[kt]);
        av = __builtin_amdgcn_mfma_f32_16x16x32_bf16(Vaf[kt], tf, av, 0, 0, 0);
      }
      // |scores| <= 5.7: exp without max-subtraction
      f32x4 ev;
      #pragma unroll
      for (int ri = 0; ri < 4; ++ri) ev[ri] = fexp2(av[ri] * LOG2E);
      float ps = ev[0] + ev[1] + ev[2] + ev[3];
      ps += __shfl_xor(ps, 16);
      ps += __shfl_xor(ps, 32);
      *(f32x4*)((char*)a_s + as_st) = ev;
      if (hi == 0) S4[lo * 4 + w] = ps;
    }
    bar_lds();  // (3) e + partial sums ready

    if (t == TSEQ - 1 && tid < 256) {   // alpha output (last step only)
      const int r = tid >> 4, sg = tid & 15;
      f32x4 e4 = *(const f32x4*)((const char*)a_s + SWZ(r * 256 + sg * 16, r));
      const f32x4 s4v = *(const f32x4*)(S4 + r * 4);
      const float rinv = frcp(s4v[0] + s4v[1] + s4v[2] + s4v[3]);
      *(f32x4*)(outAL + (b0 + r) * 64 + sg * 4) =
          (f32x4){e4[0] * rinv, e4[1] * rinv, e4[2] * rinv, e4[3] * rinv};
    }

    // ---- inline xg = (e*rinv)*x + W-GEMM (all 8 waves) ----
    {
      const f32x4 s4v = *(const f32x4*)(S4 + lo * 4);
      const float rinv = frcp(s4v[0] + s4v[1] + s4v[2] + s4v[3]);
      #pragma unroll
      for (int kt = 0; kt < 2; ++kt) {
        const f32x4 elo = *(const f32x4*)((const char*)a_s + as_rd[kt][0]);
        const f32x4 ehi = *(const f32x4*)((const char*)a_s + as_rd[kt][1]);
        const bf16x8 xv = *(const bf16x8*)((const char*)xbuf2[0] + xoff + xa_off[kt]);
        u32x4 xu;
        xu[0] = pack2(elo[0] * rinv * bf2f((unsigned short)xv[0]),
                      elo[1] * rinv * bf2f((unsigned short)xv[1]));
        xu[1] = pack2(elo[2] * rinv * bf2f((unsigned short)xv[2]),
                      elo[3] * rinv * bf2f((unsigned short)xv[3]));
        xu[2] = pack2(ehi[0] * rinv * bf2f((unsigned short)xv[4]),
                      ehi[1] * rinv * bf2f((unsigned short)xv[5]));
        xu[3] = pack2(ehi[2] * rinv * bf2f((unsigned short)xv[6]),
                      ehi[3] * rinv * bf2f((unsigned short)xv[7]));
        const bf16x8 xgf = __builtin_bit_cast(bf16x8, xu);
        #pragma unroll
        for (int g = 0; g < 4; ++g)
          acc[g] = __builtin_amdgcn_mfma_f32_16x16x32_bf16(xgf, Wf[g][kt], acc[g], 0, 0, 0);
      }
    }

    // ---- LSTM update + state/output writes ----
    #pragma unroll
    for (int ri = 0; ri < 4; ++ri) {
      const float iv = sigm(acc[0][ri]);
      const float fv = sigm(acc[1][ri]);
      const float gv = tanh_f(acc[2][ri]);
      const float ov = sigm(acc[3][ri]);
      const float cn = fv * cst[ri] + iv * gv;
      const float hv = ov * tanh_f(cn);
      cst[ri] = cn;
      *(unsigned short*)((char*)hc + hc_h[ri]) = f2bf(hv);
      *(unsigned short*)((char*)hc + hc_c[ri]) = f2bf(cn);
      *hsP[ri] = hv;                      // fire-and-forget global store
      hsP[ri] += DHS;
      if (t == TSEQ - 1) {
        const int rr = hi * 4 + ri;
        outHT[(b0 + rr) * DHS + hid] = hv;
        outCT[(b0 + rr) * DHS + hid] = cn;
        hf[rr * 128 + hid] = hv;
      }
    }

    // ---- stage x(t+1), prefetch t+2 (never drained at barriers) ----
    {
      *(unsigned int*)((char*)xbuf2[0] + (((t + 1) & 1) << 11) + xst_off) = pack2(xf.x, xf.y);
      const int tn = t + 2;
      if (tn < TSEQ) xf = *(const float2*)(xptr + tn * DIN);
    }
    bar_lds();  // (1) end of step: hc, x(t+1) visible
  }

  // ---- y_pred = h_T @ fc_w + fc_b (waves 0..3, 4 rows each) ----
  if (w < 4) {
    const float fw0 = fcw[l], fw1 = fcw[64 + l];
    const float fb = fcb[0];
    #pragma unroll
    for (int rr = 0; rr < 4; ++rr) {
      const int r = w * 4 + rr;
      float s = hf[r * 128 + l] * fw0 + hf[r * 128 + 64 + l] * fw1;
      #pragma unroll
      for (int msk = 1; msk < 64; msk <<= 1) s += __shfl_xor(s, msk);
      if (l == 0) outY[b0 + r] = s + fb;
    }
  }
}

extern "C" void kernel_launch(void* const* d_in, const int* in_sizes, int n_in,
                              void* d_out, int out_size, void* d_ws, size_t ws_size,
                              hipStream_t stream) {
  const float* X    = (const float*)d_in[0];
  const float* W    = (const float*)d_in[1];
  const float* U    = (const float*)d_in[2];
  const float* bias = (const float*)d_in[3];
  const float* Wa   = (const float*)d_in[4];
  const float* Ua   = (const float*)d_in[5];
  const float* ba   = (const float*)d_in[6];
  const float* Va   = (const float*)d_in[7];
  const float* fcw  = (const float*)d_in[8];
  const float* fcb  = (const float*)d_in[9];
  valstm_kernel<<<16, 512, 0, stream>>>(X, W, U, bias, Wa, Ua, ba, Va, fcw, fcb, (float*)d_out);
}

// Round 4
// 954.579 us; speedup vs baseline: 1.8709x; 1.4217x over previous
//
#include <hip/hip_runtime.h>

// VALSTM: B=256, T=512, IN=64, HS=128, gates=512.
// 16 blocks x 512 threads (8 waves). Block owns 16 batch rows for all T.
// Weights resident in registers as bf16 MFMA B-fragments.
// Per step (3 raw lgkmcnt-only barriers):
//   A: [w<4: attn pre x@Wa + hc@Ua -> tanh -> ta]                  bar2
//   B: [w<4: Va^T-GEMM -> exp -> partial row sums -> u=e*x tile]
//      [all: U-GEMM (fills producer shfl-latency shadow)]          bar3
//   C: [all: W-GEMM on u, fold rinv per C-row, LSTM update -> hc]  bar1
// Softmax normalization commutes with W-GEMM (per-row scalar): consumers
// never rebuild alpha*x; producers write unnormalized e*x once.
// t=511 peeled (alpha/ht/ct/hf epilogue out of hot loop).

#define TSEQ 512
#define NB   256
#define DIN  64
#define DHS  128
#define LOG2E 1.44269504f

typedef short bf16x8 __attribute__((ext_vector_type(8)));
typedef float f32x4  __attribute__((ext_vector_type(4)));

#define SWZ(off, row) ((off) ^ (((row) & 7) << 4))

__device__ __forceinline__ void bar_lds() {
  asm volatile("s_waitcnt lgkmcnt(0)\n\ts_barrier" ::: "memory");
}

__device__ __forceinline__ float fexp2(float x) { return __builtin_amdgcn_exp2f(x); }
__device__ __forceinline__ float frcp(float x)  { return __builtin_amdgcn_rcpf(x); }
__device__ __forceinline__ float sigm(float x)   { return frcp(1.0f + fexp2(-LOG2E * x)); }
__device__ __forceinline__ float tanh_f(float x) { return 1.0f - 2.0f * frcp(1.0f + fexp2(2.0f * LOG2E * x)); }

__device__ __forceinline__ unsigned short f2bf(float f) {
  return (unsigned short)((__float_as_uint(f) + 0x8000u) >> 16);
}
__device__ __forceinline__ unsigned int pack2(float a, float b) {
  return ((__float_as_uint(a) + 0x8000u) >> 16) | ((__float_as_uint(b) + 0x8000u) & 0xffff0000u);
}
__device__ __forceinline__ float bf2f(unsigned short u) {
  return __uint_as_float(((unsigned int)u) << 16);
}

__global__ __launch_bounds__(512, 2) void valstm_kernel(
    const float* __restrict__ X,  const float* __restrict__ W,  const float* __restrict__ U,
    const float* __restrict__ bias, const float* __restrict__ Wa, const float* __restrict__ Ua,
    const float* __restrict__ ba, const float* __restrict__ Va,
    const float* __restrict__ fcw, const float* __restrict__ fcb,
    float* __restrict__ out)
{
  const int tid = threadIdx.x;
  const int w   = tid >> 6;
  const int l   = tid & 63;
  const int lo  = l & 15;
  const int hi  = l >> 4;
  const int b0  = blockIdx.x * 16;

  // ---- LDS ----
  __shared__ __align__(16) unsigned short hc[16 * 256];      // h|c bf16, stride 512B
  __shared__ __align__(16) unsigned short xbuf2[2][16 * 64]; // x bf16 dbuf, stride 128B
  __shared__ __align__(16) unsigned short ta[16 * 64];       // tanh(attn pre), stride 128B
  __shared__ __align__(16) unsigned short ubuf[16 * 64];     // e*x bf16, stride 128B
  __shared__ __align__(16) float S4[64];                     // [row][wave] exp partial sums
  __shared__ __align__(16) float hf[16 * 128];               // final-step h f32

  // ---- gate weights as B-fragments ----
  bf16x8 Uf[4][4];
  bf16x8 Wf[4][2];
  float  biasr[4];
  const int hid = 16 * w + lo;
  #pragma unroll
  for (int g = 0; g < 4; ++g) {
    const int j = g * 128 + hid;
    biasr[g] = bias[j];
    #pragma unroll
    for (int kt = 0; kt < 4; ++kt) {
      bf16x8 v;
      #pragma unroll
      for (int e = 0; e < 8; ++e) { const int k = kt * 32 + hi * 8 + e; v[e] = (short)f2bf(U[k * 512 + j]); }
      Uf[g][kt] = v;
    }
    #pragma unroll
    for (int kt = 0; kt < 2; ++kt) {
      bf16x8 v;
      #pragma unroll
      for (int e = 0; e < 8; ++e) { const int k = kt * 32 + hi * 8 + e; v[e] = (short)f2bf(W[k * 512 + j]); }
      Wf[g][kt] = v;
    }
  }

  // ---- attention weights (waves 0..3) ----
  bf16x8 Uaf[8], Waf[2], Vaf[2];
  float  bar = 0.0f;
  if (w < 4) {
    const int ja = 16 * w + lo;
    bar = ba[ja];
    #pragma unroll
    for (int kt = 0; kt < 8; ++kt) {
      bf16x8 v;
      #pragma unroll
      for (int e = 0; e < 8; ++e) { const int k = kt * 32 + hi * 8 + e; v[e] = (short)f2bf(Ua[k * 64 + ja]); }
      Uaf[kt] = v;
    }
    #pragma unroll
    for (int kt = 0; kt < 2; ++kt) {
      bf16x8 v;
      #pragma unroll
      for (int e = 0; e < 8; ++e) { const int k = kt * 32 + hi * 8 + e; v[e] = (short)f2bf(Wa[k * 64 + ja]); }
      Waf[kt] = v;
    }
    #pragma unroll
    for (int kt = 0; kt < 2; ++kt) {
      bf16x8 v;
      #pragma unroll
      for (int e = 0; e < 8; ++e) { const int k = kt * 32 + hi * 8 + e; v[e] = (short)f2bf(Va[k * 64 + ja]); }
      Vaf[kt] = v;
    }
  }

  // ---- hoisted swizzled LDS byte-offsets ----
  int haf_off[4], caf_off[4], xa_off[2];
  #pragma unroll
  for (int kt = 0; kt < 4; ++kt) {
    haf_off[kt] = SWZ(lo * 512 + (kt * 32 + hi * 8) * 2, lo);
    caf_off[kt] = SWZ(lo * 512 + ((kt + 4) * 32 + hi * 8) * 2, lo);
  }
  #pragma unroll
  for (int kt = 0; kt < 2; ++kt)
    xa_off[kt] = SWZ(lo * 128 + (kt * 32 + hi * 8) * 2, lo);   // x, ta, u fragment reads
  int ta_st[4], hc_h[4], hc_c[4];
  #pragma unroll
  for (int ri = 0; ri < 4; ++ri) {
    const int rr = hi * 4 + ri;
    ta_st[ri] = SWZ(rr * 128 + (16 * w + lo) * 2, rr);
    hc_h[ri]  = SWZ(rr * 512 + hid * 2, rr);
    hc_c[ri]  = SWZ(rr * 512 + (128 + hid) * 2, rr);
  }
  const int uq_off = SWZ(lo * 128 + (16 * w + hi * 4) * 2, lo); // producer u/x slots

  // ---- zero h,c ----
  *(f32x4*)((char*)hc + tid * 16) = (f32x4){0.f, 0.f, 0.f, 0.f};

  // ---- x staging ----
  const int xr = tid >> 5;
  const int xc = (tid & 31) * 2;
  const int xst_off = SWZ(xr * 128 + xc * 2, xr);
  const float* xptr = X + (size_t)(b0 + xr) * TSEQ * DIN + xc;
  {
    const float2 v0 = *(const float2*)(xptr + 0 * DIN);
    *(unsigned int*)((char*)xbuf2[0] + xst_off) = pack2(v0.x, v0.y);
  }
  float2 xf = *(const float2*)(xptr + 1 * DIN);

  float cst[4] = {0.f, 0.f, 0.f, 0.f};

  float* outY  = out;
  float* outHS = out + 256;
  float* outHT = out + 256 + (size_t)NB * TSEQ * DHS;
  float* outCT = outHT + NB * DHS;
  float* outAL = outCT + NB * DHS;

  float* hsP[4];
  #pragma unroll
  for (int ri = 0; ri < 4; ++ri)
    hsP[ri] = outHS + (size_t)(b0 + hi * 4 + ri) * TSEQ * DHS + hid;

  bar_lds();

  #pragma unroll 1
  for (int t = 0; t < TSEQ - 1; ++t) {
    const int xoff = (t & 1) << 11;

    bf16x8 haf[4];
    #pragma unroll
    for (int kt = 0; kt < 4; ++kt)
      haf[kt] = *(const bf16x8*)((const char*)hc + haf_off[kt]);

    // ---- A: attention pre-activation (producers only) ----
    if (w < 4) {
      __builtin_amdgcn_s_setprio(1);
      f32x4 aa = (f32x4){bar, bar, bar, bar};
      f32x4 ah = (f32x4){0.f, 0.f, 0.f, 0.f};
      f32x4 ac = (f32x4){0.f, 0.f, 0.f, 0.f};
      #pragma unroll
      for (int kt = 0; kt < 2; ++kt) {
        bf16x8 xa = *(const bf16x8*)((const char*)xbuf2[0] + xoff + xa_off[kt]);
        aa = __builtin_amdgcn_mfma_f32_16x16x32_bf16(xa, Waf[kt], aa, 0, 0, 0);
      }
      #pragma unroll
      for (int kt = 0; kt < 4; ++kt)
        ah = __builtin_amdgcn_mfma_f32_16x16x32_bf16(haf[kt], Uaf[kt], ah, 0, 0, 0);
      #pragma unroll
      for (int kt = 0; kt < 4; ++kt) {
        bf16x8 ca = *(const bf16x8*)((const char*)hc + caf_off[kt]);
        ac = __builtin_amdgcn_mfma_f32_16x16x32_bf16(ca, Uaf[kt + 4], ac, 0, 0, 0);
      }
      const f32x4 pre = aa + ah + ac;
      #pragma unroll
      for (int ri = 0; ri < 4; ++ri)
        *(unsigned short*)((char*)ta + ta_st[ri]) = f2bf(tanh_f(pre[ri]));
    }
    bar_lds();  // bar2: ta ready

    // ---- B: producers Va->exp->u ; all waves U-GEMM in the shadow ----
    if (w < 4) {
      f32x4 av = (f32x4){0.f, 0.f, 0.f, 0.f};
      #pragma unroll
      for (int kt = 0; kt < 2; ++kt) {
        bf16x8 tf = *(const bf16x8*)((const char*)ta + xa_off[kt]);
        av = __builtin_amdgcn_mfma_f32_16x16x32_bf16(Vaf[kt], tf, av, 0, 0, 0);
      }
      f32x4 ev;
      #pragma unroll
      for (int ri = 0; ri < 4; ++ri) ev[ri] = fexp2(av[ri] * LOG2E);
      float ps = ev[0] + ev[1] + ev[2] + ev[3];
      ps += __shfl_xor(ps, 16);
      ps += __shfl_xor(ps, 32);
      const unsigned long long xq = *(const unsigned long long*)((const char*)xbuf2[0] + xoff + uq_off);
      const unsigned int p0 = pack2(ev[0] * bf2f((unsigned short)xq),
                                    ev[1] * bf2f((unsigned short)(xq >> 16)));
      const unsigned int p1 = pack2(ev[2] * bf2f((unsigned short)(xq >> 32)),
                                    ev[3] * bf2f((unsigned short)(xq >> 48)));
      *(unsigned long long*)((char*)ubuf + uq_off) =
          (unsigned long long)p0 | ((unsigned long long)p1 << 32);
      if (hi == 0) S4[lo * 4 + w] = ps;
      __builtin_amdgcn_s_setprio(0);
    }
    f32x4 accU[4];
    #pragma unroll
    for (int g = 0; g < 4; ++g) {
      accU[g] = (f32x4){biasr[g], biasr[g], biasr[g], biasr[g]};
      #pragma unroll
      for (int kt = 0; kt < 4; ++kt)
        accU[g] = __builtin_amdgcn_mfma_f32_16x16x32_bf16(haf[kt], Uf[g][kt], accU[g], 0, 0, 0);
    }
    bar_lds();  // bar3: u + S4 ready

    // ---- C: W-GEMM on u, rinv fold, LSTM update ----
    f32x4 accW[4];
    #pragma unroll
    for (int g = 0; g < 4; ++g) accW[g] = (f32x4){0.f, 0.f, 0.f, 0.f};
    #pragma unroll
    for (int kt = 0; kt < 2; ++kt) {
      const bf16x8 uf = *(const bf16x8*)((const char*)ubuf + xa_off[kt]);
      #pragma unroll
      for (int g = 0; g < 4; ++g)
        accW[g] = __builtin_amdgcn_mfma_f32_16x16x32_bf16(uf, Wf[g][kt], accW[g], 0, 0, 0);
    }
    float rinv_[4];
    #pragma unroll
    for (int ri = 0; ri < 4; ++ri) {
      const f32x4 s4v = *(const f32x4*)(S4 + (hi * 4 + ri) * 4);
      rinv_[ri] = frcp(s4v[0] + s4v[1] + s4v[2] + s4v[3]);
    }
    #pragma unroll
    for (int ri = 0; ri < 4; ++ri) {
      const float iv = sigm(accW[0][ri] * rinv_[ri] + accU[0][ri]);
      const float fv = sigm(accW[1][ri] * rinv_[ri] + accU[1][ri]);
      const float gv = tanh_f(accW[2][ri] * rinv_[ri] + accU[2][ri]);
      const float ov = sigm(accW[3][ri] * rinv_[ri] + accU[3][ri]);
      const float cn = fv * cst[ri] + iv * gv;
      const float hv = ov * tanh_f(cn);
      cst[ri] = cn;
      *(unsigned short*)((char*)hc + hc_h[ri]) = f2bf(hv);
      *(unsigned short*)((char*)hc + hc_c[ri]) = f2bf(cn);
      *hsP[ri] = hv;
      hsP[ri] += DHS;
    }

    // ---- stage x(t+1), prefetch x(min(t+2, T-1)) ----
    {
      *(unsigned int*)((char*)xbuf2[0] + (((t + 1) & 1) << 11) + xst_off) = pack2(xf.x, xf.y);
      const int tn = (t + 2 < TSEQ) ? t + 2 : TSEQ - 1;
      xf = *(const float2*)(xptr + tn * DIN);
    }
    bar_lds();  // bar1
  }

  // ==== peeled final step t = TSEQ-1 ====
  {
    const int xoff = ((TSEQ - 1) & 1) << 11;

    bf16x8 haf[4];
    #pragma unroll
    for (int kt = 0; kt < 4; ++kt)
      haf[kt] = *(const bf16x8*)((const char*)hc + haf_off[kt]);

    if (w < 4) {
      f32x4 aa = (f32x4){bar, bar, bar, bar};
      f32x4 ah = (f32x4){0.f, 0.f, 0.f, 0.f};
      f32x4 ac = (f32x4){0.f, 0.f, 0.f, 0.f};
      #pragma unroll
      for (int kt = 0; kt < 2; ++kt) {
        bf16x8 xa = *(const bf16x8*)((const char*)xbuf2[0] + xoff + xa_off[kt]);
        aa = __builtin_amdgcn_mfma_f32_16x16x32_bf16(xa, Waf[kt], aa, 0, 0, 0);
      }
      #pragma unroll
      for (int kt = 0; kt < 4; ++kt)
        ah = __builtin_amdgcn_mfma_f32_16x16x32_bf16(haf[kt], Uaf[kt], ah, 0, 0, 0);
      #pragma unroll
      for (int kt = 0; kt < 4; ++kt) {
        bf16x8 ca = *(const bf16x8*)((const char*)hc + caf_off[kt]);
        ac = __builtin_amdgcn_mfma_f32_16x16x32_bf16(ca, Uaf[kt + 4], ac, 0, 0, 0);
      }
      const f32x4 pre = aa + ah + ac;
      #pragma unroll
      for (int ri = 0; ri < 4; ++ri)
        *(unsigned short*)((char*)ta + ta_st[ri]) = f2bf(tanh_f(pre[ri]));
    }
    bar_lds();

    f32x4 evP = (f32x4){0.f, 0.f, 0.f, 0.f};
    if (w < 4) {
      f32x4 av = (f32x4){0.f, 0.f, 0.f, 0.f};
      #pragma unroll
      for (int kt = 0; kt < 2; ++kt) {
        bf16x8 tf = *(const bf16x8*)((const char*)ta + xa_off[kt]);
        av = __builtin_amdgcn_mfma_f32_16x16x32_bf16(Vaf[kt], tf, av, 0, 0, 0);
      }
      #pragma unroll
      for (int ri = 0; ri < 4; ++ri) evP[ri] = fexp2(av[ri] * LOG2E);
      float ps = evP[0] + evP[1] + evP[2] + evP[3];
      ps += __shfl_xor(ps, 16);
      ps += __shfl_xor(ps, 32);
      const unsigned long long xq = *(const unsigned long long*)((const char*)xbuf2[0] + xoff + uq_off);
      const unsigned int p0 = pack2(evP[0] * bf2f((unsigned short)xq),
                                    evP[1] * bf2f((unsigned short)(xq >> 16)));
      const unsigned int p1 = pack2(evP[2] * bf2f((unsigned short)(xq >> 32)),
                                    evP[3] * bf2f((unsigned short)(xq >> 48)));
      *(unsigned long long*)((char*)ubuf + uq_off) =
          (unsigned long long)p0 | ((unsigned long long)p1 << 32);
      if (hi == 0) S4[lo * 4 + w] = ps;
    }
    f32x4 accU[4];
    #pragma unroll
    for (int g = 0; g < 4; ++g) {
      accU[g] = (f32x4){biasr[g], biasr[g], biasr[g], biasr[g]};
      #pragma unroll
      for (int kt = 0; kt < 4; ++kt)
        accU[g] = __builtin_amdgcn_mfma_f32_16x16x32_bf16(haf[kt], Uf[g][kt], accU[g], 0, 0, 0);
    }
    bar_lds();

    // alpha output: producers, per-lane dwordx4
    if (w < 4) {
      const f32x4 s4v = *(const f32x4*)(S4 + lo * 4);
      const float rA = frcp(s4v[0] + s4v[1] + s4v[2] + s4v[3]);
      *(f32x4*)(outAL + (b0 + lo) * 64 + 16 * w + hi * 4) =
          (f32x4){evP[0] * rA, evP[1] * rA, evP[2] * rA, evP[3] * rA};
    }

    f32x4 accW[4];
    #pragma unroll
    for (int g = 0; g < 4; ++g) accW[g] = (f32x4){0.f, 0.f, 0.f, 0.f};
    #pragma unroll
    for (int kt = 0; kt < 2; ++kt) {
      const bf16x8 uf = *(const bf16x8*)((const char*)ubuf + xa_off[kt]);
      #pragma unroll
      for (int g = 0; g < 4; ++g)
        accW[g] = __builtin_amdgcn_mfma_f32_16x16x32_bf16(uf, Wf[g][kt], accW[g], 0, 0, 0);
    }
    float rinv_[4];
    #pragma unroll
    for (int ri = 0; ri < 4; ++ri) {
      const f32x4 s4v = *(const f32x4*)(S4 + (hi * 4 + ri) * 4);
      rinv_[ri] = frcp(s4v[0] + s4v[1] + s4v[2] + s4v[3]);
    }
    #pragma unroll
    for (int ri = 0; ri < 4; ++ri) {
      const int rr = hi * 4 + ri;
      const float iv = sigm(accW[0][ri] * rinv_[ri] + accU[0][ri]);
      const float fv = sigm(accW[1][ri] * rinv_[ri] + accU[1][ri]);
      const float gv = tanh_f(accW[2][ri] * rinv_[ri] + accU[2][ri]);
      const float ov = sigm(accW[3][ri] * rinv_[ri] + accU[3][ri]);
      const float cn = fv * cst[ri] + iv * gv;
      const float hv = ov * tanh_f(cn);
      *(unsigned short*)((char*)hc + hc_h[ri]) = f2bf(hv);
      *(unsigned short*)((char*)hc + hc_c[ri]) = f2bf(cn);
      *hsP[ri] = hv;
      outHT[(b0 + rr) * DHS + hid] = hv;
      outCT[(b0 + rr) * DHS + hid] = cn;
      hf[rr * 128 + hid] = hv;
    }
  }
  bar_lds();

  // ---- y_pred = h_T @ fc_w + fc_b (waves 0..3, 4 rows each) ----
  if (w < 4) {
    const float fw0 = fcw[l], fw1 = fcw[64 + l];
    const float fb = fcb[0];
    #pragma unroll
    for (int rr = 0; rr < 4; ++rr) {
      const int r = w * 4 + rr;
      float s = hf[r * 128 + l] * fw0 + hf[r * 128 + 64 + l] * fw1;
      #pragma unroll
      for (int msk = 1; msk < 64; msk <<= 1) s += __shfl_xor(s, msk);
      if (l == 0) outY[b0 + r] = s + fb;
    }
  }
}

extern "C" void kernel_launch(void* const* d_in, const int* in_sizes, int n_in,
                              void* d_out, int out_size, void* d_ws, size_t ws_size,
                              hipStream_t stream) {
  const float* X    = (const float*)d_in[0];
  const float* W    = (const float*)d_in[1];
  const float* U    = (const float*)d_in[2];
  const float* bias = (const float*)d_in[3];
  const float* Wa   = (const float*)d_in[4];
  const float* Ua   = (const float*)d_in[5];
  const float* ba   = (const float*)d_in[6];
  const float* Va   = (const float*)d_in[7];
  const float* fcw  = (const float*)d_in[8];
  const float* fcb  = (const float*)d_in[9];
  valstm_kernel<<<16, 512, 0, stream>>>(X, W, U, bias, Wa, Ua, ba, Va, fcw, fcb, (float*)d_out);
}